// Round 3
// baseline (601.558 us; speedup 1.0000x reference)
//
#include <hip/hip_runtime.h>
#include <hip/hip_bf16.h>
#include <cstdint>

typedef __attribute__((ext_vector_type(4))) float f32x4;
typedef __attribute__((ext_vector_type(8))) short s16x8;

#define LOG2E 1.44269504088896340736f

#define WAITV0  asm volatile("s_waitcnt vmcnt(0)" ::: "memory")
#define WAITV4  asm volatile("s_waitcnt vmcnt(4)" ::: "memory")
#define WAITV20 asm volatile("s_waitcnt vmcnt(20)" ::: "memory")

__device__ __forceinline__ unsigned short f2bf(float f) {
    unsigned int u = __builtin_bit_cast(unsigned int, f);
    u += 0x7FFFu + ((u >> 16) & 1u);
    return (unsigned short)(u >> 16);
}
__device__ __forceinline__ float bf2f(unsigned short u) {
    return __builtin_bit_cast(float, (unsigned int)u << 16);
}
__device__ __forceinline__ void gload_lds16(const void* g, void* l) {
    __builtin_amdgcn_global_load_lds(
        (const __attribute__((address_space(1))) unsigned int*)g,
        (__attribute__((address_space(3))) unsigned int*)l, 16, 0, 0);
}

// ---------------- prep kernels ----------------

__global__ void convert_x_kernel(const float* __restrict__ x,
                                 unsigned short* __restrict__ xb, int n4) {
    int i = blockIdx.x * blockDim.x + threadIdx.x;
    if (i < n4) {
        const float4 v = reinterpret_cast<const float4*>(x)[i];
        ushort4 o;
        o.x = f2bf(v.x); o.y = f2bf(v.y); o.z = f2bf(v.z); o.w = f2bf(v.w);
        reinterpret_cast<ushort4*>(xb)[i] = o;
    }
}

__global__ void transpose_w_kernel(const float* __restrict__ Wq,
                                   const float* __restrict__ Wk,
                                   const float* __restrict__ Wv,
                                   unsigned short* __restrict__ WT) {
    int i = blockIdx.x * blockDim.x + threadIdx.x;
    int m = i >> 18;
    int r = i & 262143;
    int n = r & 511;
    int k = r >> 9;
    const float* W = (m == 0) ? Wq : (m == 1) ? Wk : Wv;
    WT[(m << 18) + n * 512 + k] = f2bf(W[k * 512 + n]);
}

// ---------------- projection GEMM ----------------
__global__ __launch_bounds__(256, 2) void proj_gemm_kernel(
    const unsigned short* __restrict__ xb,
    const unsigned short* __restrict__ WT,
    const float* __restrict__ bq, const float* __restrict__ bk, const float* __restrict__ bv,
    unsigned short* __restrict__ Qb, unsigned short* __restrict__ Kb,
    unsigned short* __restrict__ VT)
{
    const int z = blockIdx.z;
    const unsigned short* Wt = WT + (z << 18);
    const float* bias = (z == 0) ? bq : (z == 1) ? bk : bv;

    const int gm = blockIdx.x * 128;
    const int gn = blockIdx.y * 128;
    const int wave = threadIdx.x >> 6, lane = threadIdx.x & 63;
    const int wr = wave >> 1, wc = wave & 1;
    const int lr = lane & 15, lg = lane >> 4;
    const int row0 = gm + wr * 64;
    const int col0 = gn + wc * 64;

    f32x4 acc[4][4];
    #pragma unroll
    for (int mi = 0; mi < 4; mi++)
        #pragma unroll
        for (int ni = 0; ni < 4; ni++)
            acc[mi][ni] = (f32x4){0.f, 0.f, 0.f, 0.f};

    for (int k0 = 0; k0 < 512; k0 += 32) {
        s16x8 a[4], b[4];
        #pragma unroll
        for (int mi = 0; mi < 4; mi++)
            a[mi] = *reinterpret_cast<const s16x8*>(xb + (size_t)(row0 + mi * 16 + lr) * 512 + k0 + lg * 8);
        #pragma unroll
        for (int ni = 0; ni < 4; ni++)
            b[ni] = *reinterpret_cast<const s16x8*>(Wt + (size_t)(col0 + ni * 16 + lr) * 512 + k0 + lg * 8);
        #pragma unroll
        for (int mi = 0; mi < 4; mi++)
            #pragma unroll
            for (int ni = 0; ni < 4; ni++)
                acc[mi][ni] = __builtin_amdgcn_mfma_f32_16x16x32_bf16(a[mi], b[ni], acc[mi][ni], 0, 0, 0);
    }

    #pragma unroll
    for (int ni = 0; ni < 4; ni++) {
        const int col = col0 + ni * 16 + lr;
        const float bs = bias[col];
        #pragma unroll
        for (int mi = 0; mi < 4; mi++) {
            const int rowb = row0 + mi * 16 + lg * 4;
            if (z == 2) {
                unsigned short h[4];
                #pragma unroll
                for (int j = 0; j < 4; j++) h[j] = f2bf(acc[mi][ni][j] + bs);
                const int bb = rowb >> 11;
                const int nn = rowb & 2047;
                ushort4 o; o.x = h[0]; o.y = h[1]; o.z = h[2]; o.w = h[3];
                *reinterpret_cast<ushort4*>(VT + (size_t)bb * (512 * 2048) + (size_t)col * 2048 + nn) = o;
            } else {
                unsigned short* dst = (z == 0) ? Qb : Kb;
                #pragma unroll
                for (int j = 0; j < 4; j++)
                    dst[(size_t)(rowb + j) * 512 + col] = f2bf(acc[mi][ni][j] + bs);
            }
        }
    }
}

// ---------------- fused masked attention (kv-split flash, counted-vmcnt pipeline) ----------------
// grid (8 batch, 32 qtile, 2 kvhalf); 4 waves x 16 q-rows; kv tiles of 64.
// 3-buffer LDS ring of 16KB d-chunks, depth-2 prefetch, raw barriers + counted vmcnt.
__global__ __launch_bounds__(256, 2) void attn_kernel(
    const unsigned short* __restrict__ Qb,
    const unsigned short* __restrict__ Kb,
    const unsigned short* __restrict__ VTb,
    const float* __restrict__ adj,
    const float* __restrict__ scale_p, const float* __restrict__ width_p,
    unsigned short* __restrict__ Op,
    float* __restrict__ Mp, float* __restrict__ Lp)
{
    const int b    = blockIdx.x;
    const int qt   = blockIdx.y;
    const int kvh  = blockIdx.z;
    const int wave = threadIdx.x >> 6;
    const int lane = threadIdx.x & 63;
    const int lr   = lane & 15;
    const int lg   = lane >> 4;

    const float scl = *scale_p;
    const float nw  = -LOG2E / (*width_p);
    const float cf  = 0.044194173824159216f * LOG2E;

    const int q0 = qt * 64 + wave * 16;
    const unsigned short* Qrow = Qb + ((size_t)b * 2048 + q0) * 512;
    const char* Kg = (const char*)Kb  + ((size_t)b * 2048 + (size_t)kvh * 1024) * 1024;
    const char* Vg = (const char*)VTb + ((size_t)b * 512 * 2048 + (size_t)kvh * 1024) * 2;
    const float* adj_b = adj + (size_t)b * 2048 * 2048
                       + (size_t)(q0 + lg * 4) * 2048 + (size_t)kvh * 1024 + lr;

    __shared__ __align__(16) char chunk[3][16384];
    __shared__ __align__(16) unsigned short p_lds[4][16][72];

    const int slot_base = wave * 4;
    auto stage_k = [&](int kv0, int dc, char* dst) {
        #pragma unroll
        for (int i = 0; i < 4; i++) {
            const int slot = slot_base + i;
            const int row  = slot * 4 + (lane >> 4);
            const int colb = (lane & 15) * 16;
            gload_lds16(Kg + (size_t)(kv0 + row) * 1024 + dc * 256 + (colb ^ ((row & 7) << 4)),
                        dst + slot * 1024);
        }
    };
    auto stage_v = [&](int kv0, int dc, char* dst) {
        #pragma unroll
        for (int i = 0; i < 4; i++) {
            const int slot = slot_base + i;
            const int row  = slot * 8 + (lane >> 3);
            const int colb = (lane & 7) * 16;
            gload_lds16(Vg + (size_t)(dc * 128 + row) * 4096 + (size_t)kv0 * 2
                           + (colb ^ ((row & 7) << 4)),
                        dst + slot * 1024);
        }
    };

    s16x8 qf[16];
    #pragma unroll
    for (int ks = 0; ks < 16; ks++)
        qf[ks] = *reinterpret_cast<const s16x8*>(Qrow + (size_t)lr * 512 + ks * 32 + lg * 8);

    f32x4 oacc[32];
    #pragma unroll
    for (int i = 0; i < 32; i++) oacc[i] = (f32x4){0.f, 0.f, 0.f, 0.f};
    float m_[4] = {-1e30f, -1e30f, -1e30f, -1e30f};
    float l_[4] = {0.f, 0.f, 0.f, 0.f};

    // prologue: stage phase 0 (K dc0 -> buf0) and phase 1 (K dc1 -> buf1)
    stage_k(0, 0, &chunk[0][0]);
    stage_k(0, 1, &chunk[1][0]);
    WAITV0;
    __builtin_amdgcn_s_barrier();

    int rcur = 0;   // ring index of phase (t,0)
    for (int t = 0; t < 16; ++t) {
        const int kv0 = t * 64;
        float av[4][4];
        f32x4 sacc[4];
        #pragma unroll
        for (int nt = 0; nt < 4; nt++) sacc[nt] = (f32x4){0.f, 0.f, 0.f, 0.f};

        #pragma unroll
        for (int s = 0; s < 8; ++s) {
            const int cb = (rcur + s) % 3;
            const int ib = (rcur + s + 2) % 3;
            char* dst = &chunk[ib][0];

            // ---- issue staging for phase P+2 ----
            if      (s == 0) stage_k(kv0, 2, dst);
            else if (s == 1) stage_k(kv0, 3, dst);
            else if (s == 2) stage_v(kv0, 0, dst);
            else if (s == 3) stage_v(kv0, 1, dst);
            else if (s == 4) stage_v(kv0, 2, dst);
            else if (s == 5) stage_v(kv0, 3, dst);
            else if (s == 6) { if (t < 15) stage_k(kv0 + 64, 0, dst); }
            else             { if (t < 15) stage_k(kv0 + 64, 1, dst); }

            // ---- adj loads for THIS tile (issued s==1, drained by s==2-end wait) ----
            if (s == 1) {
                #pragma unroll
                for (int nt = 0; nt < 4; nt++)
                    #pragma unroll
                    for (int j = 0; j < 4; j++)
                        av[nt][j] = adj_b[(size_t)j * 2048 + kv0 + nt * 16];
            }

            // ---- compute phase from buf cb ----
            if (s < 4) {
                const char* kb_ = &chunk[cb][0];
                __builtin_amdgcn_s_setprio(1);
                #pragma unroll
                for (int ks = 0; ks < 4; ks++) {
                    const s16x8 a = qf[s * 4 + ks];
                    #pragma unroll
                    for (int nt = 0; nt < 4; nt++) {
                        const int row = nt * 16 + lr;
                        const int cbyte = ks * 64 + lg * 16;
                        const s16x8 kf = *reinterpret_cast<const s16x8*>(
                            kb_ + row * 256 + (cbyte ^ ((row & 7) << 4)));
                        sacc[nt] = __builtin_amdgcn_mfma_f32_16x16x32_bf16(a, kf, sacc[nt], 0, 0, 0);
                    }
                }
                __builtin_amdgcn_s_setprio(0);

                if (s == 3) {
                    // mask + online softmax + stage P through per-wave LDS
                    #pragma unroll
                    for (int nt = 0; nt < 4; nt++)
                        #pragma unroll
                        for (int j = 0; j < 4; j++) {
                            const float d = av[nt][j] - scl;
                            sacc[nt][j] = sacc[nt][j] * cf * exp2f(d * d * nw);
                        }
                    float corr[4];
                    #pragma unroll
                    for (int j = 0; j < 4; j++) {
                        float v = fmaxf(fmaxf(sacc[0][j], sacc[1][j]), fmaxf(sacc[2][j], sacc[3][j]));
                        #pragma unroll
                        for (int sh = 1; sh < 16; sh <<= 1) v = fmaxf(v, __shfl_xor(v, sh, 64));
                        const float mn = fmaxf(m_[j], v);
                        corr[j] = exp2f(m_[j] - mn);
                        m_[j] = mn;
                    }
                    const bool need = __any(corr[0] < 1.f || corr[1] < 1.f || corr[2] < 1.f || corr[3] < 1.f);
                    if (need) {
                        #pragma unroll
                        for (int f = 0; f < 32; f++)
                            #pragma unroll
                            for (int j = 0; j < 4; j++) oacc[f][j] *= corr[j];
                    }
                    #pragma unroll
                    for (int j = 0; j < 4; j++) {
                        float rs = 0.f;
                        #pragma unroll
                        for (int nt = 0; nt < 4; nt++) {
                            const float p = exp2f(sacc[nt][j] - m_[j]);
                            p_lds[wave][lg * 4 + j][nt * 16 + lr] = f2bf(p);
                            rs += p;
                        }
                        #pragma unroll
                        for (int sh = 1; sh < 16; sh <<= 1) rs += __shfl_xor(rs, sh, 64);
                        l_[j] = l_[j] * corr[j] + rs;
                    }
                }
            } else {
                const int dc = s - 4;
                const char* vb_ = &chunk[cb][0];
                __builtin_amdgcn_s_setprio(1);
                #pragma unroll
                for (int ks2 = 0; ks2 < 2; ks2++) {
                    const s16x8 pa = *reinterpret_cast<const s16x8*>(&p_lds[wave][lr][ks2 * 32 + lg * 8]);
                    #pragma unroll
                    for (int df2 = 0; df2 < 8; df2++) {
                        const int row = df2 * 16 + lr;
                        const int cbyte = ks2 * 64 + lg * 16;
                        const s16x8 vf = *reinterpret_cast<const s16x8*>(
                            vb_ + row * 128 + (cbyte ^ ((row & 7) << 4)));
                        oacc[dc * 8 + df2] = __builtin_amdgcn_mfma_f32_16x16x32_bf16(pa, vf, oacc[dc * 8 + df2], 0, 0, 0);
                    }
                }
                __builtin_amdgcn_s_setprio(0);
            }

            // ---- counted wait + barrier ----
            if (s == 1) { WAITV20; }
            else if (s == 6) { if (t < 15) { WAITV4; } else { WAITV0; } }
            else if (s == 7) { if (t < 15) { WAITV4; } }
            else { WAITV4; }
            __builtin_amdgcn_s_barrier();
        }
        rcur += 2; if (rcur >= 3) rcur -= 3;
    }

    // ---- epilogue: unnormalized partial O (bf16) + m/l ----
    const size_t prow = (size_t)kvh * 16384 + (size_t)b * 2048 + q0 + lg * 4;
    unsigned short* op = Op + prow * 512 + lr;
    #pragma unroll
    for (int df = 0; df < 32; df++)
        #pragma unroll
        for (int j = 0; j < 4; j++)
            op[(size_t)j * 512 + df * 16] = f2bf(oacc[df][j]);
    if (lr == 0) {
        #pragma unroll
        for (int j = 0; j < 4; j++) {
            Mp[prow + j] = m_[j];
            Lp[prow + j] = l_[j];
        }
    }
}

// ---------------- combine ----------------
__global__ void combine_kernel(const unsigned short* __restrict__ Op,
                               const float* __restrict__ Mp, const float* __restrict__ Lp,
                               float* __restrict__ out) {
    const int idx = blockIdx.x * 256 + threadIdx.x;
    const int r   = idx >> 6;
    const int c8  = (idx & 63) * 8;
    const float m0 = Mp[r], m1 = Mp[16384 + r];
    const float l0 = Lp[r], l1 = Lp[16384 + r];
    const float M  = fmaxf(m0, m1);
    const float e0 = exp2f(m0 - M), e1 = exp2f(m1 - M);
    const float invL = 1.f / (e0 * l0 + e1 * l1);
    const s16x8 a = *reinterpret_cast<const s16x8*>(Op + (size_t)r * 512 + c8);
    const s16x8 bq = *reinterpret_cast<const s16x8*>(Op + (size_t)16384 * 512 + (size_t)r * 512 + c8);
    float o[8];
    #pragma unroll
    for (int i = 0; i < 8; i++)
        o[i] = (bf2f((unsigned short)a[i]) * e0 + bf2f((unsigned short)bq[i]) * e1) * invL;
    f32x4* dst = reinterpret_cast<f32x4*>(out + (size_t)r * 512 + c8);
    dst[0] = (f32x4){o[0], o[1], o[2], o[3]};
    dst[1] = (f32x4){o[4], o[5], o[6], o[7]};
}

// ---------------- launch ----------------

extern "C" void kernel_launch(void* const* d_in, const int* in_sizes, int n_in,
                              void* d_out, int out_size, void* d_ws, size_t ws_size,
                              hipStream_t stream) {
    const float* x     = (const float*)d_in[0];
    const float* adj   = (const float*)d_in[1];
    const float* Wq    = (const float*)d_in[2];
    const float* bq    = (const float*)d_in[3];
    const float* Wk    = (const float*)d_in[4];
    const float* bk    = (const float*)d_in[5];
    const float* Wv    = (const float*)d_in[6];
    const float* bv    = (const float*)d_in[7];
    const float* scale = (const float*)d_in[8];
    const float* width = (const float*)d_in[9];

    char* ws = (char*)d_ws;
    unsigned short* xb = (unsigned short*)(ws);
    unsigned short* WT = (unsigned short*)(ws + 16777216);
    unsigned short* Qb = (unsigned short*)(ws + 18350080);
    unsigned short* Kb = (unsigned short*)(ws + 35127296);
    unsigned short* VT = (unsigned short*)(ws + 51904512);
    unsigned short* Op = (unsigned short*)(ws + 68681728);
    float*          Mp = (float*)(ws + 102236160);
    float*          Lp = (float*)(ws + 102367232);
    float* out = (float*)d_out;

    hipLaunchKernelGGL(convert_x_kernel, dim3(8192), dim3(256), 0, stream, x, xb, 8388608 / 4);
    hipLaunchKernelGGL(transpose_w_kernel, dim3(3072), dim3(256), 0, stream, Wq, Wk, Wv, WT);
    hipLaunchKernelGGL(proj_gemm_kernel, dim3(128, 4, 3), dim3(256), 0, stream,
                       xb, WT, bq, bk, bv, Qb, Kb, VT);
    hipLaunchKernelGGL(attn_kernel, dim3(8, 32, 2), dim3(256), 0, stream,
                       Qb, Kb, VT, adj, scale, width, Op, Mp, Lp);
    hipLaunchKernelGGL(combine_kernel, dim3(4096), dim3(256), 0, stream, Op, Mp, Lp, out);
}

// Round 4
// 597.349 us; speedup vs baseline: 1.0070x; 1.0070x over previous
//
#include <hip/hip_runtime.h>
#include <hip/hip_bf16.h>
#include <cstdint>

typedef __attribute__((ext_vector_type(4))) float f32x4;
typedef __attribute__((ext_vector_type(8))) short s16x8;

#define LOG2E 1.44269504088896340736f

#define WAITV0  asm volatile("s_waitcnt vmcnt(0)" ::: "memory")
#define WAITV4  asm volatile("s_waitcnt vmcnt(4)" ::: "memory")
#define WAITV20 asm volatile("s_waitcnt vmcnt(20)" ::: "memory")

__device__ __forceinline__ unsigned short f2bf(float f) {
    unsigned int u = __builtin_bit_cast(unsigned int, f);
    u += 0x7FFFu + ((u >> 16) & 1u);
    return (unsigned short)(u >> 16);
}
__device__ __forceinline__ float bf2f(unsigned short u) {
    return __builtin_bit_cast(float, (unsigned int)u << 16);
}
__device__ __forceinline__ void gload_lds16(const void* g, void* l) {
    __builtin_amdgcn_global_load_lds(
        (const __attribute__((address_space(1))) unsigned int*)g,
        (__attribute__((address_space(3))) unsigned int*)l, 16, 0, 0);
}

// ---------------- prep kernels ----------------

__global__ void convert_x_kernel(const float* __restrict__ x,
                                 unsigned short* __restrict__ xb, int n4) {
    int i = blockIdx.x * blockDim.x + threadIdx.x;
    if (i < n4) {
        const float4 v = reinterpret_cast<const float4*>(x)[i];
        ushort4 o;
        o.x = f2bf(v.x); o.y = f2bf(v.y); o.z = f2bf(v.z); o.w = f2bf(v.w);
        reinterpret_cast<ushort4*>(xb)[i] = o;
    }
}

__global__ void transpose_w_kernel(const float* __restrict__ Wq,
                                   const float* __restrict__ Wk,
                                   const float* __restrict__ Wv,
                                   unsigned short* __restrict__ WT) {
    int i = blockIdx.x * blockDim.x + threadIdx.x;
    int m = i >> 18;
    int r = i & 262143;
    int n = r & 511;
    int k = r >> 9;
    const float* W = (m == 0) ? Wq : (m == 1) ? Wk : Wv;
    WT[(m << 18) + n * 512 + k] = f2bf(W[k * 512 + n]);
}

// ---------------- projection GEMM ----------------
__global__ __launch_bounds__(256, 2) void proj_gemm_kernel(
    const unsigned short* __restrict__ xb,
    const unsigned short* __restrict__ WT,
    const float* __restrict__ bq, const float* __restrict__ bk, const float* __restrict__ bv,
    unsigned short* __restrict__ Qb, unsigned short* __restrict__ Kb,
    unsigned short* __restrict__ VT)
{
    const int z = blockIdx.z;
    const unsigned short* Wt = WT + (z << 18);
    const float* bias = (z == 0) ? bq : (z == 1) ? bk : bv;

    const int gm = blockIdx.x * 128;
    const int gn = blockIdx.y * 128;
    const int wave = threadIdx.x >> 6, lane = threadIdx.x & 63;
    const int wr = wave >> 1, wc = wave & 1;
    const int lr = lane & 15, lg = lane >> 4;
    const int row0 = gm + wr * 64;
    const int col0 = gn + wc * 64;

    f32x4 acc[4][4];
    #pragma unroll
    for (int mi = 0; mi < 4; mi++)
        #pragma unroll
        for (int ni = 0; ni < 4; ni++)
            acc[mi][ni] = (f32x4){0.f, 0.f, 0.f, 0.f};

    for (int k0 = 0; k0 < 512; k0 += 32) {
        s16x8 a[4], b[4];
        #pragma unroll
        for (int mi = 0; mi < 4; mi++)
            a[mi] = *reinterpret_cast<const s16x8*>(xb + (size_t)(row0 + mi * 16 + lr) * 512 + k0 + lg * 8);
        #pragma unroll
        for (int ni = 0; ni < 4; ni++)
            b[ni] = *reinterpret_cast<const s16x8*>(Wt + (size_t)(col0 + ni * 16 + lr) * 512 + k0 + lg * 8);
        #pragma unroll
        for (int mi = 0; mi < 4; mi++)
            #pragma unroll
            for (int ni = 0; ni < 4; ni++)
                acc[mi][ni] = __builtin_amdgcn_mfma_f32_16x16x32_bf16(a[mi], b[ni], acc[mi][ni], 0, 0, 0);
    }

    #pragma unroll
    for (int ni = 0; ni < 4; ni++) {
        const int col = col0 + ni * 16 + lr;
        const float bs = bias[col];
        #pragma unroll
        for (int mi = 0; mi < 4; mi++) {
            const int rowb = row0 + mi * 16 + lg * 4;
            if (z == 2) {
                unsigned short h[4];
                #pragma unroll
                for (int j = 0; j < 4; j++) h[j] = f2bf(acc[mi][ni][j] + bs);
                const int bb = rowb >> 11;
                const int nn = rowb & 2047;
                ushort4 o; o.x = h[0]; o.y = h[1]; o.z = h[2]; o.w = h[3];
                *reinterpret_cast<ushort4*>(VT + (size_t)bb * (512 * 2048) + (size_t)col * 2048 + nn) = o;
            } else {
                unsigned short* dst = (z == 0) ? Qb : Kb;
                #pragma unroll
                for (int j = 0; j < 4; j++)
                    dst[(size_t)(rowb + j) * 512 + col] = f2bf(acc[mi][ni][j] + bs);
            }
        }
    }
}

// ---------------- fused masked attention ----------------
// grid (16 = b*2+kvh, 32 qtile); 4 waves x 16 q-rows; kv tiles of 64.
// 3-buffer LDS ring, depth-2 prefetch, counted vmcnt. adj/Q nontemporal.
// Coalesced nontemporal Op epilogue via LDS transpose.
__global__ __launch_bounds__(256, 2) void attn_kernel(
    const unsigned short* __restrict__ Qb,
    const unsigned short* __restrict__ Kb,
    const unsigned short* __restrict__ VTb,
    const float* __restrict__ adj,
    const float* __restrict__ scale_p, const float* __restrict__ width_p,
    unsigned short* __restrict__ Op,
    float* __restrict__ Mp, float* __restrict__ Lp)
{
    const int bk   = blockIdx.x;      // b*2 + kvh  -> XCD = bk & 7
    const int b    = bk >> 1;
    const int kvh  = bk & 1;
    const int qt   = blockIdx.y;
    const int wave = threadIdx.x >> 6;
    const int lane = threadIdx.x & 63;
    const int lr   = lane & 15;
    const int lg   = lane >> 4;

    const float scl = *scale_p;
    const float nw  = -LOG2E / (*width_p);
    const float cf  = 0.044194173824159216f * LOG2E;

    const int q0 = qt * 64 + wave * 16;
    const unsigned short* Qrow = Qb + ((size_t)b * 2048 + q0) * 512;
    const char* Kg = (const char*)Kb  + ((size_t)b * 2048 + (size_t)kvh * 1024) * 1024;
    const char* Vg = (const char*)VTb + ((size_t)b * 512 * 2048 + (size_t)kvh * 1024) * 2;
    const float* adj_b = adj + (size_t)b * 2048 * 2048
                       + (size_t)(q0 + lg * 4) * 2048 + (size_t)kvh * 1024 + lr;

    __shared__ __align__(16) char chunk[3][16384];
    __shared__ __align__(16) unsigned short p_lds[4][16][72];

    const int slot_base = wave * 4;
    auto stage_k = [&](int kv0, int dc, char* dst) {
        #pragma unroll
        for (int i = 0; i < 4; i++) {
            const int slot = slot_base + i;
            const int row  = slot * 4 + (lane >> 4);
            const int colb = (lane & 15) * 16;
            gload_lds16(Kg + (size_t)(kv0 + row) * 1024 + dc * 256 + (colb ^ ((row & 7) << 4)),
                        dst + slot * 1024);
        }
    };
    auto stage_v = [&](int kv0, int dc, char* dst) {
        #pragma unroll
        for (int i = 0; i < 4; i++) {
            const int slot = slot_base + i;
            const int row  = slot * 8 + (lane >> 3);
            const int colb = (lane & 7) * 16;
            gload_lds16(Vg + (size_t)(dc * 128 + row) * 4096 + (size_t)kv0 * 2
                           + (colb ^ ((row & 7) << 4)),
                        dst + slot * 1024);
        }
    };

    // Q fragments: single-use per block -> nontemporal
    s16x8 qf[16];
    #pragma unroll
    for (int ks = 0; ks < 16; ks++)
        qf[ks] = __builtin_nontemporal_load(
            reinterpret_cast<const s16x8*>(Qrow + (size_t)lr * 512 + ks * 32 + lg * 8));

    f32x4 oacc[32];
    #pragma unroll
    for (int i = 0; i < 32; i++) oacc[i] = (f32x4){0.f, 0.f, 0.f, 0.f};
    float m_[4] = {-1e30f, -1e30f, -1e30f, -1e30f};
    float l_[4] = {0.f, 0.f, 0.f, 0.f};

    stage_k(0, 0, &chunk[0][0]);
    stage_k(0, 1, &chunk[1][0]);
    WAITV0;
    __builtin_amdgcn_s_barrier();

    int rcur = 0;
    for (int t = 0; t < 16; ++t) {
        const int kv0 = t * 64;
        float av[4][4];
        f32x4 sacc[4];
        #pragma unroll
        for (int nt = 0; nt < 4; nt++) sacc[nt] = (f32x4){0.f, 0.f, 0.f, 0.f};

        #pragma unroll
        for (int s = 0; s < 8; ++s) {
            const int cb = (rcur + s) % 3;
            const int ib = (rcur + s + 2) % 3;
            char* dst = &chunk[ib][0];

            if      (s == 0) stage_k(kv0, 2, dst);
            else if (s == 1) stage_k(kv0, 3, dst);
            else if (s == 2) stage_v(kv0, 0, dst);
            else if (s == 3) stage_v(kv0, 1, dst);
            else if (s == 4) stage_v(kv0, 2, dst);
            else if (s == 5) stage_v(kv0, 3, dst);
            else if (s == 6) { if (t < 15) stage_k(kv0 + 64, 0, dst); }
            else             { if (t < 15) stage_k(kv0 + 64, 1, dst); }

            if (s == 1) {   // adj: single-use stream, nontemporal
                #pragma unroll
                for (int nt = 0; nt < 4; nt++)
                    #pragma unroll
                    for (int j = 0; j < 4; j++)
                        av[nt][j] = __builtin_nontemporal_load(
                            &adj_b[(size_t)j * 2048 + kv0 + nt * 16]);
            }

            if (s < 4) {
                const char* kb_ = &chunk[cb][0];
                __builtin_amdgcn_s_setprio(1);
                #pragma unroll
                for (int ks = 0; ks < 4; ks++) {
                    const s16x8 a = qf[s * 4 + ks];
                    #pragma unroll
                    for (int nt = 0; nt < 4; nt++) {
                        const int row = nt * 16 + lr;
                        const int cbyte = ks * 64 + lg * 16;
                        const s16x8 kf = *reinterpret_cast<const s16x8*>(
                            kb_ + row * 256 + (cbyte ^ ((row & 7) << 4)));
                        sacc[nt] = __builtin_amdgcn_mfma_f32_16x16x32_bf16(a, kf, sacc[nt], 0, 0, 0);
                    }
                }
                __builtin_amdgcn_s_setprio(0);

                if (s == 3) {
                    #pragma unroll
                    for (int nt = 0; nt < 4; nt++)
                        #pragma unroll
                        for (int j = 0; j < 4; j++) {
                            const float d = av[nt][j] - scl;
                            sacc[nt][j] = sacc[nt][j] * cf * exp2f(d * d * nw);
                        }
                    float corr[4];
                    #pragma unroll
                    for (int j = 0; j < 4; j++) {
                        float v = fmaxf(fmaxf(sacc[0][j], sacc[1][j]), fmaxf(sacc[2][j], sacc[3][j]));
                        #pragma unroll
                        for (int sh = 1; sh < 16; sh <<= 1) v = fmaxf(v, __shfl_xor(v, sh, 64));
                        const float mn = fmaxf(m_[j], v);
                        corr[j] = exp2f(m_[j] - mn);
                        m_[j] = mn;
                    }
                    const bool need = __any(corr[0] < 1.f || corr[1] < 1.f || corr[2] < 1.f || corr[3] < 1.f);
                    if (need) {
                        #pragma unroll
                        for (int f = 0; f < 32; f++)
                            #pragma unroll
                            for (int j = 0; j < 4; j++) oacc[f][j] *= corr[j];
                    }
                    #pragma unroll
                    for (int j = 0; j < 4; j++) {
                        float rs = 0.f;
                        #pragma unroll
                        for (int nt = 0; nt < 4; nt++) {
                            const float p = exp2f(sacc[nt][j] - m_[j]);
                            p_lds[wave][lg * 4 + j][nt * 16 + lr] = f2bf(p);
                            rs += p;
                        }
                        #pragma unroll
                        for (int sh = 1; sh < 16; sh <<= 1) rs += __shfl_xor(rs, sh, 64);
                        l_[j] = l_[j] * corr[j] + rs;
                    }
                }
            } else {
                const int dc = s - 4;
                const char* vb_ = &chunk[cb][0];
                __builtin_amdgcn_s_setprio(1);
                #pragma unroll
                for (int ks2 = 0; ks2 < 2; ks2++) {
                    const s16x8 pa = *reinterpret_cast<const s16x8*>(&p_lds[wave][lr][ks2 * 32 + lg * 8]);
                    #pragma unroll
                    for (int df2 = 0; df2 < 8; df2++) {
                        const int row = df2 * 16 + lr;
                        const int cbyte = ks2 * 64 + lg * 16;
                        const s16x8 vf = *reinterpret_cast<const s16x8*>(
                            vb_ + row * 128 + (cbyte ^ ((row & 7) << 4)));
                        oacc[dc * 8 + df2] = __builtin_amdgcn_mfma_f32_16x16x32_bf16(pa, vf, oacc[dc * 8 + df2], 0, 0, 0);
                    }
                }
                __builtin_amdgcn_s_setprio(0);
            }

            if (s == 1) { WAITV20; }
            else if (s == 6) { if (t < 15) { WAITV4; } else { WAITV0; } }
            else if (s == 7) { if (t < 15) { WAITV4; } }
            else { WAITV4; }
            __builtin_amdgcn_s_barrier();
        }
        rcur += 2; if (rcur >= 3) rcur -= 3;
    }

    // ---- epilogue: LDS-transpose -> full-line nontemporal Op stores ----
    // (all waves are past the final barrier; chunk is dead, reuse per-wave slice)
    unsigned short* lds_t = (unsigned short*)&chunk[0][0] + (size_t)wave * 4224; // 16 rows x 264
    const size_t prow0 = (size_t)kvh * 16384 + (size_t)b * 2048 + q0;

    #pragma unroll
    for (int h = 0; h < 2; ++h) {
        #pragma unroll
        for (int dd = 0; dd < 16; ++dd) {
            const int df = h * 16 + dd;
            #pragma unroll
            for (int j = 0; j < 4; ++j)
                lds_t[(lg * 4 + j) * 264 + dd * 16 + lr] = f2bf(oacc[df][j]);
        }
        #pragma unroll
        for (int g = 0; g < 2; ++g) {
            const int r16  = g * 8 + (lane >> 3);
            const int colu = (lane & 7) * 8;
            unsigned short* oprow = Op + (prow0 + r16) * 512 + h * 256;
            #pragma unroll
            for (int k = 0; k < 4; ++k) {
                const s16x8 v = *reinterpret_cast<const s16x8*>(&lds_t[r16 * 264 + colu + k * 64]);
                __builtin_nontemporal_store(v, reinterpret_cast<s16x8*>(oprow + colu + k * 64));
            }
        }
    }
    if (lr == 0) {
        #pragma unroll
        for (int j = 0; j < 4; j++) {
            Mp[prow0 + lg * 4 + j] = m_[j];
            Lp[prow0 + lg * 4 + j] = l_[j];
        }
    }
}

// ---------------- combine ----------------
__global__ void combine_kernel(const unsigned short* __restrict__ Op,
                               const float* __restrict__ Mp, const float* __restrict__ Lp,
                               float* __restrict__ out) {
    const int idx = blockIdx.x * 256 + threadIdx.x;
    const int r   = idx >> 6;
    const int c8  = (idx & 63) * 8;
    const float m0 = Mp[r], m1 = Mp[16384 + r];
    const float l0 = Lp[r], l1 = Lp[16384 + r];
    const float M  = fmaxf(m0, m1);
    const float e0 = exp2f(m0 - M), e1 = exp2f(m1 - M);
    const float invL = 1.f / (e0 * l0 + e1 * l1);
    const s16x8 a = __builtin_nontemporal_load(
        reinterpret_cast<const s16x8*>(Op + (size_t)r * 512 + c8));
    const s16x8 bq = __builtin_nontemporal_load(
        reinterpret_cast<const s16x8*>(Op + (size_t)16384 * 512 + (size_t)r * 512 + c8));
    float o[8];
    #pragma unroll
    for (int i = 0; i < 8; i++)
        o[i] = (bf2f((unsigned short)a[i]) * e0 + bf2f((unsigned short)bq[i]) * e1) * invL;
    f32x4* dst = reinterpret_cast<f32x4*>(out + (size_t)r * 512 + c8);
    __builtin_nontemporal_store((f32x4){o[0], o[1], o[2], o[3]}, dst);
    __builtin_nontemporal_store((f32x4){o[4], o[5], o[6], o[7]}, dst + 1);
}

// ---------------- launch ----------------

extern "C" void kernel_launch(void* const* d_in, const int* in_sizes, int n_in,
                              void* d_out, int out_size, void* d_ws, size_t ws_size,
                              hipStream_t stream) {
    const float* x     = (const float*)d_in[0];
    const float* adj   = (const float*)d_in[1];
    const float* Wq    = (const float*)d_in[2];
    const float* bq    = (const float*)d_in[3];
    const float* Wk    = (const float*)d_in[4];
    const float* bk    = (const float*)d_in[5];
    const float* Wv    = (const float*)d_in[6];
    const float* bv    = (const float*)d_in[7];
    const float* scale = (const float*)d_in[8];
    const float* width = (const float*)d_in[9];

    char* ws = (char*)d_ws;
    unsigned short* xb = (unsigned short*)(ws);
    unsigned short* WT = (unsigned short*)(ws + 16777216);
    unsigned short* Qb = (unsigned short*)(ws + 18350080);
    unsigned short* Kb = (unsigned short*)(ws + 35127296);
    unsigned short* VT = (unsigned short*)(ws + 51904512);
    unsigned short* Op = (unsigned short*)(ws + 68681728);
    float*          Mp = (float*)(ws + 102236160);
    float*          Lp = (float*)(ws + 102367232);
    float* out = (float*)d_out;

    hipLaunchKernelGGL(convert_x_kernel, dim3(8192), dim3(256), 0, stream, x, xb, 8388608 / 4);
    hipLaunchKernelGGL(transpose_w_kernel, dim3(3072), dim3(256), 0, stream, Wq, Wk, Wv, WT);
    hipLaunchKernelGGL(proj_gemm_kernel, dim3(128, 4, 3), dim3(256), 0, stream,
                       xb, WT, bq, bk, bv, Qb, Kb, VT);
    hipLaunchKernelGGL(attn_kernel, dim3(16, 32), dim3(256), 0, stream,
                       Qb, Kb, VT, adj, scale, width, Op, Mp, Lp);
    hipLaunchKernelGGL(combine_kernel, dim3(4096), dim3(256), 0, stream, Op, Mp, Lp, out);
}

// Round 5
// 290.073 us; speedup vs baseline: 2.0738x; 2.0593x over previous
//
#include <hip/hip_runtime.h>
#include <hip/hip_bf16.h>
#include <cstdint>

typedef __attribute__((ext_vector_type(4))) float f32x4;
typedef __attribute__((ext_vector_type(8))) short s16x8;

#define LOG2E 1.44269504088896340736f

#define WAITV0 asm volatile("s_waitcnt vmcnt(0)" ::: "memory")
#define WAITV2 asm volatile("s_waitcnt vmcnt(2)" ::: "memory")
#define WAITLG asm volatile("s_waitcnt lgkmcnt(0)" ::: "memory")

__device__ __forceinline__ unsigned short f2bf(float f) {
    unsigned int u = __builtin_bit_cast(unsigned int, f);
    u += 0x7FFFu + ((u >> 16) & 1u);
    return (unsigned short)(u >> 16);
}
__device__ __forceinline__ float bf2f(unsigned short u) {
    return __builtin_bit_cast(float, (unsigned int)u << 16);
}
__device__ __forceinline__ void gload_lds16(const void* g, void* l) {
    __builtin_amdgcn_global_load_lds(
        (const __attribute__((address_space(1))) unsigned int*)g,
        (__attribute__((address_space(3))) unsigned int*)l, 16, 0, 0);
}
__device__ __forceinline__ int m3(int v) {   // v in [0, 11]
    if (v >= 9) v -= 9;
    if (v >= 6) v -= 6;
    if (v >= 3) v -= 3;
    return v;
}

// ---------------- prep kernels ----------------

__global__ void convert_x_kernel(const float* __restrict__ x,
                                 unsigned short* __restrict__ xb, int n4) {
    int i = blockIdx.x * blockDim.x + threadIdx.x;
    if (i < n4) {
        const float4 v = reinterpret_cast<const float4*>(x)[i];
        ushort4 o;
        o.x = f2bf(v.x); o.y = f2bf(v.y); o.z = f2bf(v.z); o.w = f2bf(v.w);
        reinterpret_cast<ushort4*>(xb)[i] = o;
    }
}

__global__ void transpose_w_kernel(const float* __restrict__ Wq,
                                   const float* __restrict__ Wk,
                                   const float* __restrict__ Wv,
                                   unsigned short* __restrict__ WT) {
    int i = blockIdx.x * blockDim.x + threadIdx.x;
    int m = i >> 18;
    int r = i & 262143;
    int n = r & 511;
    int k = r >> 9;
    const float* W = (m == 0) ? Wq : (m == 1) ? Wk : Wv;
    WT[(m << 18) + n * 512 + k] = f2bf(W[k * 512 + n]);
}

// ---------------- projection GEMM ----------------
__global__ __launch_bounds__(256, 2) void proj_gemm_kernel(
    const unsigned short* __restrict__ xb,
    const unsigned short* __restrict__ WT,
    const float* __restrict__ bq, const float* __restrict__ bk, const float* __restrict__ bv,
    unsigned short* __restrict__ Qb, unsigned short* __restrict__ Kb,
    unsigned short* __restrict__ VT)
{
    const int z = blockIdx.z;
    const unsigned short* Wt = WT + (z << 18);
    const float* bias = (z == 0) ? bq : (z == 1) ? bk : bv;

    const int gm = blockIdx.x * 128;
    const int gn = blockIdx.y * 128;
    const int wave = threadIdx.x >> 6, lane = threadIdx.x & 63;
    const int wr = wave >> 1, wc = wave & 1;
    const int lr = lane & 15, lg = lane >> 4;
    const int row0 = gm + wr * 64;
    const int col0 = gn + wc * 64;

    f32x4 acc[4][4];
    #pragma unroll
    for (int mi = 0; mi < 4; mi++)
        #pragma unroll
        for (int ni = 0; ni < 4; ni++)
            acc[mi][ni] = (f32x4){0.f, 0.f, 0.f, 0.f};

    for (int k0 = 0; k0 < 512; k0 += 32) {
        s16x8 a[4], b[4];
        #pragma unroll
        for (int mi = 0; mi < 4; mi++)
            a[mi] = *reinterpret_cast<const s16x8*>(xb + (size_t)(row0 + mi * 16 + lr) * 512 + k0 + lg * 8);
        #pragma unroll
        for (int ni = 0; ni < 4; ni++)
            b[ni] = *reinterpret_cast<const s16x8*>(Wt + (size_t)(col0 + ni * 16 + lr) * 512 + k0 + lg * 8);
        #pragma unroll
        for (int mi = 0; mi < 4; mi++)
            #pragma unroll
            for (int ni = 0; ni < 4; ni++)
                acc[mi][ni] = __builtin_amdgcn_mfma_f32_16x16x32_bf16(a[mi], b[ni], acc[mi][ni], 0, 0, 0);
    }

    #pragma unroll
    for (int ni = 0; ni < 4; ni++) {
        const int col = col0 + ni * 16 + lr;
        const float bs = bias[col];
        #pragma unroll
        for (int mi = 0; mi < 4; mi++) {
            const int rowb = row0 + mi * 16 + lg * 4;
            if (z == 2) {
                unsigned short h[4];
                #pragma unroll
                for (int j = 0; j < 4; j++) h[j] = f2bf(acc[mi][ni][j] + bs);
                const int bb = rowb >> 11;
                const int nn = rowb & 2047;
                ushort4 o; o.x = h[0]; o.y = h[1]; o.z = h[2]; o.w = h[3];
                *reinterpret_cast<ushort4*>(VT + (size_t)bb * (512 * 2048) + (size_t)col * 2048 + nn) = o;
            } else {
                unsigned short* dst = (z == 0) ? Qb : Kb;
                #pragma unroll
                for (int j = 0; j < 4; j++)
                    dst[(size_t)(rowb + j) * 512 + col] = f2bf(acc[mi][ni][j] + bs);
            }
        }
    }
}

// ---------------- fused masked attention: wave-specialized ----------------
// grid (16 = b*2+kvh, 32 qtile); 8 waves: 0-3 score (QK+softmax), 4-7 output (PV).
// d-chunks of 64 (8KB); K ring-3 (S-stream), V ring-3 (O-stream), depth-2 counted vmcnt.
// P + corr handed through double-buffered LDS; O runs one kv-tile behind S.
__global__ __launch_bounds__(512, 2) void attn_kernel(
    const unsigned short* __restrict__ Qb,
    const unsigned short* __restrict__ Kb,
    const unsigned short* __restrict__ VTb,
    const float* __restrict__ adj,
    const float* __restrict__ scale_p, const float* __restrict__ width_p,
    unsigned short* __restrict__ Op,
    float* __restrict__ Mp, float* __restrict__ Lp)
{
    const int bk   = blockIdx.x;
    const int b    = bk >> 1;
    const int kvh  = bk & 1;
    const int qt   = blockIdx.y;
    const int wave = threadIdx.x >> 6;
    const int lane = threadIdx.x & 63;
    const int lr   = lane & 15;
    const int lg   = lane >> 4;

    // LDS carve: kring 3x8192 | vring 3x8192 | pbuf [2][4][16][72] | corr [2][64]
    __shared__ __align__(16) char smem[68096];
    char* kring = smem;
    char* vring = smem + 24576;
    unsigned short (*pbuf)[4][16][72] = (unsigned short (*)[4][16][72])(smem + 49152);
    float* corrbuf = (float*)(smem + 67584);

    if (wave < 4) {
        // ================= S path: QK^T + mask + online softmax =================
        const int sw = wave;
        const int q0 = qt * 64 + sw * 16;
        const unsigned short* Qrow = Qb + ((size_t)b * 2048 + q0) * 512;
        const char* Kg = (const char*)Kb + ((size_t)b * 2048 + (size_t)kvh * 1024) * 1024;
        const float* adj_b = adj + (size_t)b * 2048 * 2048
                           + (size_t)(q0 + lg * 4) * 2048 + (size_t)kvh * 1024 + lr;
        const float scl = *scale_p;
        const float nw  = -LOG2E / (*width_p);
        const float cf  = 0.044194173824159216f * LOG2E;

        // stage K chunk c (tile c>>3, d-chunk c&7) into ring slot
        auto stage_k = [&](int slot, int c) {
            char* dstb = kring + slot * 8192;
            const int kvt = (c >> 3) * 64;
            const int dcb = (c & 7) * 128;
            #pragma unroll
            for (int i = 0; i < 2; i++) {
                const int sl  = sw * 2 + i;
                const int row = sl * 8 + (lane >> 3);
                const int colb = (lane & 7) * 16;
                gload_lds16(Kg + (size_t)(kvt + row) * 1024 + dcb + (colb ^ ((row & 7) << 4)),
                            dstb + sl * 1024);
            }
        };

        s16x8 qf[16];
        #pragma unroll
        for (int ks = 0; ks < 16; ks++)
            qf[ks] = __builtin_nontemporal_load(
                reinterpret_cast<const s16x8*>(Qrow + (size_t)lr * 512 + ks * 32 + lg * 8));

        f32x4 sacc[4];
        #pragma unroll
        for (int nt = 0; nt < 4; nt++) sacc[nt] = (f32x4){0.f, 0.f, 0.f, 0.f};
        float m_[4] = {-1e30f, -1e30f, -1e30f, -1e30f};
        float l_[4] = {0.f, 0.f, 0.f, 0.f};

        stage_k(0, 0);
        stage_k(1, 1);
        WAITV0;
        __builtin_amdgcn_s_barrier();

        int rcur = 0;   // (t*8) % 3
        for (int t = 0; t < 16; ++t) {
            const int kv0 = t * 64;
            float av[4][4];
            #pragma unroll
            for (int p = 0; p < 8; ++p) {
                if (p == 6) {
                    #pragma unroll
                    for (int nt = 0; nt < 4; nt++)
                        #pragma unroll
                        for (int j = 0; j < 4; j++)
                            av[nt][j] = __builtin_nontemporal_load(
                                &adj_b[(size_t)j * 2048 + kv0 + nt * 16]);
                }
                const bool do_stage = (t < 15) || (p < 6);
                if (do_stage) stage_k(m3(rcur + p + 2), t * 8 + p + 2);

                const char* kb_ = kring + m3(rcur + p) * 8192;
                __builtin_amdgcn_s_setprio(1);
                #pragma unroll
                for (int ks = 0; ks < 2; ks++) {
                    const s16x8 a = qf[p * 2 + ks];
                    #pragma unroll
                    for (int nt = 0; nt < 4; nt++) {
                        const int row = nt * 16 + lr;
                        const int cbyte = ks * 64 + lg * 16;
                        const s16x8 kf = *reinterpret_cast<const s16x8*>(
                            kb_ + row * 128 + (cbyte ^ ((row & 7) << 4)));
                        sacc[nt] = __builtin_amdgcn_mfma_f32_16x16x32_bf16(a, kf, sacc[nt], 0, 0, 0);
                    }
                }
                __builtin_amdgcn_s_setprio(0);

                if (p == 7) {
                    // mask + online softmax; hand off P and corr via LDS
                    #pragma unroll
                    for (int nt = 0; nt < 4; nt++)
                        #pragma unroll
                        for (int j = 0; j < 4; j++) {
                            const float d = av[nt][j] - scl;
                            sacc[nt][j] = sacc[nt][j] * cf * exp2f(d * d * nw);
                        }
                    float corr[4];
                    #pragma unroll
                    for (int j = 0; j < 4; j++) {
                        float v = fmaxf(fmaxf(sacc[0][j], sacc[1][j]), fmaxf(sacc[2][j], sacc[3][j]));
                        #pragma unroll
                        for (int sh = 1; sh < 16; sh <<= 1) v = fmaxf(v, __shfl_xor(v, sh, 64));
                        const float mn = fmaxf(m_[j], v);
                        corr[j] = exp2f(m_[j] - mn);
                        m_[j] = mn;
                    }
                    #pragma unroll
                    for (int j = 0; j < 4; j++) {
                        float rs = 0.f;
                        #pragma unroll
                        for (int nt = 0; nt < 4; nt++) {
                            const float pv = exp2f(sacc[nt][j] - m_[j]);
                            pbuf[t & 1][sw][lg * 4 + j][nt * 16 + lr] = f2bf(pv);
                            rs += pv;
                        }
                        #pragma unroll
                        for (int sh = 1; sh < 16; sh <<= 1) rs += __shfl_xor(rs, sh, 64);
                        l_[j] = l_[j] * corr[j] + rs;
                    }
                    if (lr == 0) {
                        #pragma unroll
                        for (int j = 0; j < 4; j++)
                            corrbuf[(t & 1) * 64 + sw * 16 + lg * 4 + j] = corr[j];
                    }
                    #pragma unroll
                    for (int nt = 0; nt < 4; nt++) sacc[nt] = (f32x4){0.f, 0.f, 0.f, 0.f};
                    WAITLG;   // drain pbuf/corr ds_writes before barrier
                }
                if (do_stage) { WAITV2; } else { WAITV0; }
                __builtin_amdgcn_s_barrier();
            }
            rcur += 2; if (rcur >= 3) rcur -= 3;
        }
        // trailing step t=16: barrier-match while O-waves finish PV(15)
        #pragma unroll
        for (int p = 0; p < 8; ++p) {
            WAITV0;
            __builtin_amdgcn_s_barrier();
        }
        const size_t prow0 = (size_t)kvh * 16384 + (size_t)b * 2048 + q0;
        if (lr == 0) {
            #pragma unroll
            for (int j = 0; j < 4; j++) {
                Mp[prow0 + lg * 4 + j] = m_[j];
                Lp[prow0 + lg * 4 + j] = l_[j];
            }
        }
    } else {
        // ================= O path: PV accumulate =================
        const int ow = wave - 4;
        const int q0 = qt * 64 + ow * 16;
        const char* Vg = (const char*)VTb + ((size_t)b * 512 * 2048 + (size_t)kvh * 1024) * 2;

        // stage V chunk c (tile c>>3, d-chunk c&7) into ring slot
        auto stage_v = [&](int slot, int c) {
            char* dstb = vring + slot * 8192;
            const int kvt = (c >> 3) * 64;
            const int dr0 = (c & 7) * 64;
            #pragma unroll
            for (int i = 0; i < 2; i++) {
                const int sl  = ow * 2 + i;
                const int row = sl * 8 + (lane >> 3);
                const int colb = (lane & 7) * 16;
                gload_lds16(Vg + (size_t)(dr0 + row) * 4096 + (size_t)kvt * 2 + (colb ^ ((row & 7) << 4)),
                            dstb + sl * 1024);
            }
        };

        f32x4 oacc[32];
        #pragma unroll
        for (int i = 0; i < 32; i++) oacc[i] = (f32x4){0.f, 0.f, 0.f, 0.f};
        s16x8 pa0{}, pa1{};

        __builtin_amdgcn_s_barrier();   // match S prologue

        // t = 0: no PV yet; start V stream at g=6,7 (chunks 0,1)
        #pragma unroll
        for (int p = 0; p < 8; ++p) {
            if (p == 6) stage_v(0, 0);
            if (p == 7) stage_v(1, 1);
            WAITV2;
            __builtin_amdgcn_s_barrier();
        }

        int rcur = 2;   // (t*8)%3 for t=1
        for (int t = 1; t < 17; ++t) {
            #pragma unroll
            for (int p = 0; p < 8; ++p) {
                const bool do_stage = (t < 16) || (p < 6);
                if (do_stage) stage_v(m3(rcur + p), t * 8 + p - 6);

                if (p == 0) {
                    const float* cl = corrbuf + ((t - 1) & 1) * 64 + ow * 16;
                    float c_[4];
                    #pragma unroll
                    for (int j = 0; j < 4; j++) c_[j] = cl[lg * 4 + j];
                    const unsigned short* pb = &pbuf[(t - 1) & 1][ow][0][0];
                    pa0 = *reinterpret_cast<const s16x8*>(pb + lr * 72 + lg * 8);
                    pa1 = *reinterpret_cast<const s16x8*>(pb + lr * 72 + 32 + lg * 8);
                    const bool need = __any(c_[0] < 1.f || c_[1] < 1.f || c_[2] < 1.f || c_[3] < 1.f);
                    if (need) {
                        #pragma unroll
                        for (int f = 0; f < 32; f++)
                            #pragma unroll
                            for (int j = 0; j < 4; j++) oacc[f][j] *= c_[j];
                    }
                }

                const char* vb_ = vring + m3(rcur + p + 1) * 8192;
                __builtin_amdgcn_s_setprio(1);
                #pragma unroll
                for (int ks2 = 0; ks2 < 2; ks2++) {
                    const s16x8 pa = (ks2 == 0) ? pa0 : pa1;
                    #pragma unroll
                    for (int df2 = 0; df2 < 4; df2++) {
                        const int row = df2 * 16 + lr;
                        const int cbyte = ks2 * 64 + lg * 16;
                        const s16x8 vf = *reinterpret_cast<const s16x8*>(
                            vb_ + row * 128 + (cbyte ^ ((row & 7) << 4)));
                        oacc[p * 4 + df2] = __builtin_amdgcn_mfma_f32_16x16x32_bf16(pa, vf, oacc[p * 4 + df2], 0, 0, 0);
                    }
                }
                __builtin_amdgcn_s_setprio(0);

                if (do_stage) { WAITV2; } else { WAITV0; }
                __builtin_amdgcn_s_barrier();
            }
            rcur += 2; if (rcur >= 3) rcur -= 3;
        }

        // ---- epilogue: LDS-transpose -> full-line nontemporal Op stores ----
        unsigned short* lds_t = (unsigned short*)smem + (size_t)ow * 4224;  // 16 x 264
        const size_t prow0 = (size_t)kvh * 16384 + (size_t)b * 2048 + q0;
        #pragma unroll
        for (int h = 0; h < 2; ++h) {
            #pragma unroll
            for (int dd = 0; dd < 16; ++dd) {
                const int df = h * 16 + dd;
                #pragma unroll
                for (int j = 0; j < 4; ++j)
                    lds_t[(lg * 4 + j) * 264 + dd * 16 + lr] = f2bf(oacc[df][j]);
            }
            #pragma unroll
            for (int g2 = 0; g2 < 2; ++g2) {
                const int r16  = g2 * 8 + (lane >> 3);
                const int colu = (lane & 7) * 8;
                unsigned short* oprow = Op + (prow0 + r16) * 512 + h * 256;
                #pragma unroll
                for (int k = 0; k < 4; ++k) {
                    const s16x8 v = *reinterpret_cast<const s16x8*>(&lds_t[r16 * 264 + colu + k * 64]);
                    __builtin_nontemporal_store(v, reinterpret_cast<s16x8*>(oprow + colu + k * 64));
                }
            }
        }
    }
}

// ---------------- combine ----------------
__global__ void combine_kernel(const unsigned short* __restrict__ Op,
                               const float* __restrict__ Mp, const float* __restrict__ Lp,
                               float* __restrict__ out) {
    const int idx = blockIdx.x * 256 + threadIdx.x;
    const int r   = idx >> 6;
    const int c8  = (idx & 63) * 8;
    const float m0 = Mp[r], m1 = Mp[16384 + r];
    const float l0 = Lp[r], l1 = Lp[16384 + r];
    const float M  = fmaxf(m0, m1);
    const float e0 = exp2f(m0 - M), e1 = exp2f(m1 - M);
    const float invL = 1.f / (e0 * l0 + e1 * l1);
    const s16x8 a = __builtin_nontemporal_load(
        reinterpret_cast<const s16x8*>(Op + (size_t)r * 512 + c8));
    const s16x8 bq = __builtin_nontemporal_load(
        reinterpret_cast<const s16x8*>(Op + (size_t)16384 * 512 + (size_t)r * 512 + c8));
    float o[8];
    #pragma unroll
    for (int i = 0; i < 8; i++)
        o[i] = (bf2f((unsigned short)a[i]) * e0 + bf2f((unsigned short)bq[i]) * e1) * invL;
    f32x4* dst = reinterpret_cast<f32x4*>(out + (size_t)r * 512 + c8);
    __builtin_nontemporal_store((f32x4){o[0], o[1], o[2], o[3]}, dst);
    __builtin_nontemporal_store((f32x4){o[4], o[5], o[6], o[7]}, dst + 1);
}

// ---------------- launch ----------------

extern "C" void kernel_launch(void* const* d_in, const int* in_sizes, int n_in,
                              void* d_out, int out_size, void* d_ws, size_t ws_size,
                              hipStream_t stream) {
    const float* x     = (const float*)d_in[0];
    const float* adj   = (const float*)d_in[1];
    const float* Wq    = (const float*)d_in[2];
    const float* bq    = (const float*)d_in[3];
    const float* Wk    = (const float*)d_in[4];
    const float* bk    = (const float*)d_in[5];
    const float* Wv    = (const float*)d_in[6];
    const float* bv    = (const float*)d_in[7];
    const float* scale = (const float*)d_in[8];
    const float* width = (const float*)d_in[9];

    char* ws = (char*)d_ws;
    unsigned short* xb = (unsigned short*)(ws);
    unsigned short* WT = (unsigned short*)(ws + 16777216);
    unsigned short* Qb = (unsigned short*)(ws + 18350080);
    unsigned short* Kb = (unsigned short*)(ws + 35127296);
    unsigned short* VT = (unsigned short*)(ws + 51904512);
    unsigned short* Op = (unsigned short*)(ws + 68681728);
    float*          Mp = (float*)(ws + 102236160);
    float*          Lp = (float*)(ws + 102367232);
    float* out = (float*)d_out;

    hipLaunchKernelGGL(convert_x_kernel, dim3(8192), dim3(256), 0, stream, x, xb, 8388608 / 4);
    hipLaunchKernelGGL(transpose_w_kernel, dim3(3072), dim3(256), 0, stream, Wq, Wk, Wv, WT);
    hipLaunchKernelGGL(proj_gemm_kernel, dim3(128, 4, 3), dim3(256), 0, stream,
                       xb, WT, bq, bk, bv, Qb, Kb, VT);
    hipLaunchKernelGGL(attn_kernel, dim3(16, 32), dim3(512), 0, stream,
                       Qb, Kb, VT, adj, scale, width, Op, Mp, Lp);
    hipLaunchKernelGGL(combine_kernel, dim3(4096), dim3(256), 0, stream, Op, Mp, Lp, out);
}

// Round 9
// 240.718 us; speedup vs baseline: 2.4990x; 1.2050x over previous
//
#include <hip/hip_runtime.h>
#include <hip/hip_bf16.h>
#include <cstdint>

typedef __attribute__((ext_vector_type(4))) float f32x4;
typedef __attribute__((ext_vector_type(8))) short s16x8;

#define LOG2E 1.44269504088896340736f

#define WAITV0 asm volatile("s_waitcnt vmcnt(0)" ::: "memory")
#define WAITV2 asm volatile("s_waitcnt vmcnt(2)" ::: "memory")
#define WAITLG asm volatile("s_waitcnt lgkmcnt(0)" ::: "memory")
#define BARRIER asm volatile("s_barrier" ::: "memory")

__device__ __forceinline__ unsigned short f2bf(float f) {
    unsigned int u = __builtin_bit_cast(unsigned int, f);
    u += 0x7FFFu + ((u >> 16) & 1u);
    return (unsigned short)(u >> 16);
}
__device__ __forceinline__ float bf2f(unsigned short u) {
    return __builtin_bit_cast(float, (unsigned int)u << 16);
}
__device__ __forceinline__ void gload_lds16(const void* g, void* l) {
    __builtin_amdgcn_global_load_lds(
        (const __attribute__((address_space(1))) unsigned int*)g,
        (__attribute__((address_space(3))) unsigned int*)l, 16, 0, 0);
}
__device__ __forceinline__ int m3(int v) {   // v in [0, 11]
    if (v >= 9) v -= 9;
    if (v >= 6) v -= 6;
    if (v >= 3) v -= 3;
    return v;
}

// ---------------- prep kernels ----------------

__global__ void convert_x_kernel(const float* __restrict__ x,
                                 unsigned short* __restrict__ xb, int n4) {
    int i = blockIdx.x * blockDim.x + threadIdx.x;
    if (i < n4) {
        const float4 v = reinterpret_cast<const float4*>(x)[i];
        ushort4 o;
        o.x = f2bf(v.x); o.y = f2bf(v.y); o.z = f2bf(v.z); o.w = f2bf(v.w);
        reinterpret_cast<ushort4*>(xb)[i] = o;
    }
}

// LDS-tiled W transpose: WT[z][n][k] = W_z[k][n], coalesced both sides
__global__ void transpose_w_kernel(const float* __restrict__ Wq,
                                   const float* __restrict__ Wk,
                                   const float* __restrict__ Wv,
                                   unsigned short* __restrict__ WT) {
    const int z = blockIdx.z;
    const int n0 = blockIdx.x * 64, k0 = blockIdx.y * 64;
    const float* W = (z == 0) ? Wq : (z == 1) ? Wk : Wv;
    __shared__ float tile[64][65];
    const int tx = threadIdx.x & 63, ty = threadIdx.x >> 6;
    #pragma unroll
    for (int i = 0; i < 16; ++i) {
        const int r = i * 4 + ty;
        tile[r][tx] = W[(size_t)(k0 + r) * 512 + n0 + tx];
    }
    __syncthreads();
    #pragma unroll
    for (int i = 0; i < 16; ++i) {
        const int r = i * 4 + ty;   // n-local
        WT[(size_t)(z << 18) + (size_t)(n0 + r) * 512 + k0 + tx] = f2bf(tile[tx][r]);
    }
}

// ---------------- projection GEMM (gload_lds + double-buffer) ----------------
// 128x128 tile, BK=32, 16 K-steps. z=0 Qb, z=1 Kb (row-major), z=2 VT[b][d][n].
__global__ __launch_bounds__(256, 2) void proj_gemm_kernel(
    const unsigned short* __restrict__ xb,
    const unsigned short* __restrict__ WT,
    const float* __restrict__ bq, const float* __restrict__ bkp, const float* __restrict__ bv,
    unsigned short* __restrict__ Qb, unsigned short* __restrict__ Kb,
    unsigned short* __restrict__ VT)
{
    const int z = blockIdx.z;
    const char* Wt = (const char*)(WT + (z << 18));
    const char* Xg = (const char*)xb;
    const float* bias = (z == 0) ? bq : (z == 1) ? bkp : bv;

    const int gm = blockIdx.x * 128;
    const int gn = blockIdx.y * 128;
    const int wave = threadIdx.x >> 6, lane = threadIdx.x & 63;
    const int wr = wave >> 1, wc = wave & 1;
    const int lr = lane & 15, lg = lane >> 4;
    const int row0 = gm + wr * 64;
    const int col0 = gn + wc * 64;

    __shared__ __align__(16) char smem[36864];
    char* As = smem;            // [2][128][32] bf16 = 2 x 8192
    char* Bs = smem + 16384;    // [2][128][32] bf16

    auto stage = [&](int buf, int k0b) {   // k0b = k0*2 bytes
        #pragma unroll
        for (int i = 0; i < 2; ++i) {
            const int s = wave * 2 + i;            // 0..7
            const int row = s * 16 + (lane >> 2);  // 0..127
            const int colb = (lane & 3) * 16;      // 0..48
            gload_lds16(Xg + (size_t)(gm + row) * 1024 + k0b + colb, As + buf * 8192 + s * 1024);
            gload_lds16(Wt + (size_t)(gn + row) * 1024 + k0b + colb, Bs + buf * 8192 + s * 1024);
        }
    };

    f32x4 acc[4][4];
    #pragma unroll
    for (int mi = 0; mi < 4; mi++)
        #pragma unroll
        for (int ni = 0; ni < 4; ni++)
            acc[mi][ni] = (f32x4){0.f, 0.f, 0.f, 0.f};

    stage(0, 0);
    WAITV0;
    BARRIER;

    int buf = 0;
    for (int t = 0; t < 16; ++t) {
        if (t < 15) stage(buf ^ 1, (t + 1) * 64);
        s16x8 a[4], bfr[4];
        #pragma unroll
        for (int mi = 0; mi < 4; mi++)
            a[mi] = *reinterpret_cast<const s16x8*>(As + buf * 8192 + (wr * 64 + mi * 16 + lr) * 64 + lg * 16);
        #pragma unroll
        for (int ni = 0; ni < 4; ni++)
            bfr[ni] = *reinterpret_cast<const s16x8*>(Bs + buf * 8192 + (wc * 64 + ni * 16 + lr) * 64 + lg * 16);
        #pragma unroll
        for (int mi = 0; mi < 4; mi++)
            #pragma unroll
            for (int ni = 0; ni < 4; ni++)
                acc[mi][ni] = __builtin_amdgcn_mfma_f32_16x16x32_bf16(a[mi], bfr[ni], acc[mi][ni], 0, 0, 0);
        WAITV0;
        BARRIER;
        buf ^= 1;
    }

    // ---- epilogue: LDS transpose -> coalesced 128B-line nontemporal stores ----
    // lt row stride = 72 shorts = 144 B (16B multiple!). Stride 68 (136 B) put odd
    // rows at 8-mod-16 addresses -> misaligned ds_read_b128 -> corrupt Q/K/VT
    // (the rounds-6/7/8 failure). 64 x 72 x 2 B x 4 waves = 36864 B = exact fit.
    unsigned short* lt = (unsigned short*)smem + (size_t)wave * 4608;   // 64 x 72
    if (z < 2) {
        #pragma unroll
        for (int ni = 0; ni < 4; ni++) {
            const float bs = bias[col0 + ni * 16 + lr];
            #pragma unroll
            for (int mi = 0; mi < 4; mi++)
                #pragma unroll
                for (int j = 0; j < 4; j++)
                    lt[(mi * 16 + lg * 4 + j) * 72 + ni * 16 + lr] = f2bf(acc[mi][ni][j] + bs);
        }
        WAITLG;
        unsigned short* dst = (z == 0) ? Qb : Kb;
        #pragma unroll
        for (int g2 = 0; g2 < 8; ++g2) {
            const int r = g2 * 8 + (lane >> 3);
            const int colu = (lane & 7) * 8;
            const s16x8 v = *reinterpret_cast<const s16x8*>(&lt[r * 72 + colu]);
            __builtin_nontemporal_store(v,
                reinterpret_cast<s16x8*>(dst + (size_t)(row0 + r) * 512 + col0 + colu));
        }
    } else {
        #pragma unroll
        for (int ni = 0; ni < 4; ni++) {
            const float bs = bias[col0 + ni * 16 + lr];
            #pragma unroll
            for (int mi = 0; mi < 4; mi++)
                #pragma unroll
                for (int j = 0; j < 4; j++)
                    lt[(ni * 16 + lr) * 72 + mi * 16 + lg * 4 + j] = f2bf(acc[mi][ni][j] + bs);
        }
        WAITLG;
        const int bb = row0 >> 11;
        const int nn0 = row0 & 2047;
        #pragma unroll
        for (int g2 = 0; g2 < 8; ++g2) {
            const int c = g2 * 8 + (lane >> 3);
            const int colu = (lane & 7) * 8;
            const s16x8 v = *reinterpret_cast<const s16x8*>(&lt[c * 72 + colu]);
            __builtin_nontemporal_store(v,
                reinterpret_cast<s16x8*>(VT + (size_t)bb * (512 * 2048) + (size_t)(col0 + c) * 2048 + nn0 + colu));
        }
    }
}

// ---------------- fused masked attention: ROUND-5 VERBATIM (proven pass) ----------------
// grid (16 = b*2+kvh, 32 qtile); 8 waves: 0-3 score (QK+softmax), 4-7 output (PV).
// d-chunks of 64 (8KB); K ring-3 (S-stream), V ring-3 (O-stream), depth-2 counted vmcnt.
__global__ __launch_bounds__(512, 2) void attn_kernel(
    const unsigned short* __restrict__ Qb,
    const unsigned short* __restrict__ Kb,
    const unsigned short* __restrict__ VTb,
    const float* __restrict__ adj,
    const float* __restrict__ scale_p, const float* __restrict__ width_p,
    unsigned short* __restrict__ Op,
    float* __restrict__ Mp, float* __restrict__ Lp)
{
    const int bk   = blockIdx.x;
    const int b    = bk >> 1;
    const int kvh  = bk & 1;
    const int qt   = blockIdx.y;
    const int wave = threadIdx.x >> 6;
    const int lane = threadIdx.x & 63;
    const int lr   = lane & 15;
    const int lg   = lane >> 4;

    // LDS carve: kring 3x8192 | vring 3x8192 | pbuf [2][4][16][72] | corr [2][64]
    __shared__ __align__(16) char smem[68096];
    char* kring = smem;
    char* vring = smem + 24576;
    unsigned short (*pbuf)[4][16][72] = (unsigned short (*)[4][16][72])(smem + 49152);
    float* corrbuf = (float*)(smem + 67584);

    if (wave < 4) {
        // ================= S path: QK^T + mask + online softmax =================
        const int sw = wave;
        const int q0 = qt * 64 + sw * 16;
        const unsigned short* Qrow = Qb + ((size_t)b * 2048 + q0) * 512;
        const char* Kg = (const char*)Kb + ((size_t)b * 2048 + (size_t)kvh * 1024) * 1024;
        const float* adj_b = adj + (size_t)b * 2048 * 2048
                           + (size_t)(q0 + lg * 4) * 2048 + (size_t)kvh * 1024 + lr;
        const float scl = *scale_p;
        const float nw  = -LOG2E / (*width_p);
        const float cf  = 0.044194173824159216f * LOG2E;

        auto stage_k = [&](int slot, int c) {
            char* dstb = kring + slot * 8192;
            const int kvt = (c >> 3) * 64;
            const int dcb = (c & 7) * 128;
            #pragma unroll
            for (int i = 0; i < 2; i++) {
                const int sl  = sw * 2 + i;
                const int row = sl * 8 + (lane >> 3);
                const int colb = (lane & 7) * 16;
                gload_lds16(Kg + (size_t)(kvt + row) * 1024 + dcb + (colb ^ ((row & 7) << 4)),
                            dstb + sl * 1024);
            }
        };

        s16x8 qf[16];
        #pragma unroll
        for (int ks = 0; ks < 16; ks++)
            qf[ks] = __builtin_nontemporal_load(
                reinterpret_cast<const s16x8*>(Qrow + (size_t)lr * 512 + ks * 32 + lg * 8));

        f32x4 sacc[4];
        #pragma unroll
        for (int nt = 0; nt < 4; nt++) sacc[nt] = (f32x4){0.f, 0.f, 0.f, 0.f};
        float m_[4] = {-1e30f, -1e30f, -1e30f, -1e30f};
        float l_[4] = {0.f, 0.f, 0.f, 0.f};

        stage_k(0, 0);
        stage_k(1, 1);
        WAITV0;
        __builtin_amdgcn_s_barrier();

        int rcur = 0;   // (t*8) % 3
        for (int t = 0; t < 16; ++t) {
            const int kv0 = t * 64;
            float av[4][4];
            #pragma unroll
            for (int p = 0; p < 8; ++p) {
                if (p == 6) {
                    #pragma unroll
                    for (int nt = 0; nt < 4; nt++)
                        #pragma unroll
                        for (int j = 0; j < 4; j++)
                            av[nt][j] = __builtin_nontemporal_load(
                                &adj_b[(size_t)j * 2048 + kv0 + nt * 16]);
                }
                const bool do_stage = (t < 15) || (p < 6);
                if (do_stage) stage_k(m3(rcur + p + 2), t * 8 + p + 2);

                const char* kb_ = kring + m3(rcur + p) * 8192;
                __builtin_amdgcn_s_setprio(1);
                #pragma unroll
                for (int ks = 0; ks < 2; ks++) {
                    const s16x8 a = qf[p * 2 + ks];
                    #pragma unroll
                    for (int nt = 0; nt < 4; nt++) {
                        const int row = nt * 16 + lr;
                        const int cbyte = ks * 64 + lg * 16;
                        const s16x8 kf = *reinterpret_cast<const s16x8*>(
                            kb_ + row * 128 + (cbyte ^ ((row & 7) << 4)));
                        sacc[nt] = __builtin_amdgcn_mfma_f32_16x16x32_bf16(a, kf, sacc[nt], 0, 0, 0);
                    }
                }
                __builtin_amdgcn_s_setprio(0);

                if (p == 7) {
                    // mask + online softmax; hand off P and corr via LDS
                    #pragma unroll
                    for (int nt = 0; nt < 4; nt++)
                        #pragma unroll
                        for (int j = 0; j < 4; j++) {
                            const float d = av[nt][j] - scl;
                            sacc[nt][j] = sacc[nt][j] * cf * exp2f(d * d * nw);
                        }
                    float corr[4];
                    #pragma unroll
                    for (int j = 0; j < 4; j++) {
                        float v = fmaxf(fmaxf(sacc[0][j], sacc[1][j]), fmaxf(sacc[2][j], sacc[3][j]));
                        #pragma unroll
                        for (int sh = 1; sh < 16; sh <<= 1) v = fmaxf(v, __shfl_xor(v, sh, 64));
                        const float mn = fmaxf(m_[j], v);
                        corr[j] = exp2f(m_[j] - mn);
                        m_[j] = mn;
                    }
                    #pragma unroll
                    for (int j = 0; j < 4; j++) {
                        float rs = 0.f;
                        #pragma unroll
                        for (int nt = 0; nt < 4; nt++) {
                            const float pv = exp2f(sacc[nt][j] - m_[j]);
                            pbuf[t & 1][sw][lg * 4 + j][nt * 16 + lr] = f2bf(pv);
                            rs += pv;
                        }
                        #pragma unroll
                        for (int sh = 1; sh < 16; sh <<= 1) rs += __shfl_xor(rs, sh, 64);
                        l_[j] = l_[j] * corr[j] + rs;
                    }
                    if (lr == 0) {
                        #pragma unroll
                        for (int j = 0; j < 4; j++)
                            corrbuf[(t & 1) * 64 + sw * 16 + lg * 4 + j] = corr[j];
                    }
                    #pragma unroll
                    for (int nt = 0; nt < 4; nt++) sacc[nt] = (f32x4){0.f, 0.f, 0.f, 0.f};
                    WAITLG;   // drain pbuf/corr ds_writes before barrier
                }
                if (do_stage) { WAITV2; } else { WAITV0; }
                __builtin_amdgcn_s_barrier();
            }
            rcur += 2; if (rcur >= 3) rcur -= 3;
        }
        // trailing step t=16: barrier-match while O-waves finish PV(15)
        #pragma unroll
        for (int p = 0; p < 8; ++p) {
            WAITV0;
            __builtin_amdgcn_s_barrier();
        }
        const size_t prow0 = (size_t)kvh * 16384 + (size_t)b * 2048 + q0;
        if (lr == 0) {
            #pragma unroll
            for (int j = 0; j < 4; j++) {
                Mp[prow0 + lg * 4 + j] = m_[j];
                Lp[prow0 + lg * 4 + j] = l_[j];
            }
        }
    } else {
        // ================= O path: PV accumulate =================
        const int ow = wave - 4;
        const int q0 = qt * 64 + ow * 16;
        const char* Vg = (const char*)VTb + ((size_t)b * 512 * 2048 + (size_t)kvh * 1024) * 2;

        auto stage_v = [&](int slot, int c) {
            char* dstb = vring + slot * 8192;
            const int kvt = (c >> 3) * 64;
            const int dr0 = (c & 7) * 64;
            #pragma unroll
            for (int i = 0; i < 2; i++) {
                const int sl  = ow * 2 + i;
                const int row = sl * 8 + (lane >> 3);
                const int colb = (lane & 7) * 16;
                gload_lds16(Vg + (size_t)(dr0 + row) * 4096 + (size_t)kvt * 2 + (colb ^ ((row & 7) << 4)),
                            dstb + sl * 1024);
            }
        };

        f32x4 oacc[32];
        #pragma unroll
        for (int i = 0; i < 32; i++) oacc[i] = (f32x4){0.f, 0.f, 0.f, 0.f};
        s16x8 pa0{}, pa1{};

        __builtin_amdgcn_s_barrier();   // match S prologue

        // t = 0: no PV yet; start V stream at p=6,7 (chunks 0,1)
        #pragma unroll
        for (int p = 0; p < 8; ++p) {
            if (p == 6) stage_v(0, 0);
            if (p == 7) stage_v(1, 1);
            WAITV2;
            __builtin_amdgcn_s_barrier();
        }

        int rcur = 2;   // (t*8)%3 for t=1
        for (int t = 1; t < 17; ++t) {
            #pragma unroll
            for (int p = 0; p < 8; ++p) {
                const bool do_stage = (t < 16) || (p < 6);
                if (do_stage) stage_v(m3(rcur + p), t * 8 + p - 6);

                if (p == 0) {
                    const float* cl = corrbuf + ((t - 1) & 1) * 64 + ow * 16;
                    float c_[4];
                    #pragma unroll
                    for (int j = 0; j < 4; j++) c_[j] = cl[lg * 4 + j];
                    const unsigned short* pb = &pbuf[(t - 1) & 1][ow][0][0];
                    pa0 = *reinterpret_cast<const s16x8*>(pb + lr * 72 + lg * 8);
                    pa1 = *reinterpret_cast<const s16x8*>(pb + lr * 72 + 32 + lg * 8);
                    const bool need = __any(c_[0] < 1.f || c_[1] < 1.f || c_[2] < 1.f || c_[3] < 1.f);
                    if (need) {
                        #pragma unroll
                        for (int f = 0; f < 32; f++)
                            #pragma unroll
                            for (int j = 0; j < 4; j++) oacc[f][j] *= c_[j];
                    }
                }

                const char* vb_ = vring + m3(rcur + p + 1) * 8192;
                __builtin_amdgcn_s_setprio(1);
                #pragma unroll
                for (int ks2 = 0; ks2 < 2; ks2++) {
                    const s16x8 pa = (ks2 == 0) ? pa0 : pa1;
                    #pragma unroll
                    for (int df2 = 0; df2 < 4; df2++) {
                        const int row = df2 * 16 + lr;
                        const int cbyte = ks2 * 64 + lg * 16;
                        const s16x8 vf = *reinterpret_cast<const s16x8*>(
                            vb_ + row * 128 + (cbyte ^ ((row & 7) << 4)));
                        oacc[p * 4 + df2] = __builtin_amdgcn_mfma_f32_16x16x32_bf16(pa, vf, oacc[p * 4 + df2], 0, 0, 0);
                    }
                }
                __builtin_amdgcn_s_setprio(0);

                if (do_stage) { WAITV2; } else { WAITV0; }
                __builtin_amdgcn_s_barrier();
            }
            rcur += 2; if (rcur >= 3) rcur -= 3;
        }

        // ---- epilogue: LDS-transpose -> full-line nontemporal Op stores ----
        unsigned short* lds_t = (unsigned short*)smem + (size_t)ow * 4224;  // 16 x 264
        const size_t prow0 = (size_t)kvh * 16384 + (size_t)b * 2048 + q0;
        #pragma unroll
        for (int h = 0; h < 2; ++h) {
            #pragma unroll
            for (int dd = 0; dd < 16; ++dd) {
                const int df = h * 16 + dd;
                #pragma unroll
                for (int j = 0; j < 4; ++j)
                    lds_t[(lg * 4 + j) * 264 + dd * 16 + lr] = f2bf(oacc[df][j]);
            }
            #pragma unroll
            for (int g2 = 0; g2 < 2; ++g2) {
                const int r16  = g2 * 8 + (lane >> 3);
                const int colu = (lane & 7) * 8;
                unsigned short* oprow = Op + (prow0 + r16) * 512 + h * 256;
                #pragma unroll
                for (int k = 0; k < 4; ++k) {
                    const s16x8 v = *reinterpret_cast<const s16x8*>(&lds_t[r16 * 264 + colu + k * 64]);
                    __builtin_nontemporal_store(v, reinterpret_cast<s16x8*>(oprow + colu + k * 64));
                }
            }
        }
    }
}

// ---------------- combine ----------------
__global__ void combine_kernel(const unsigned short* __restrict__ Op,
                               const float* __restrict__ Mp, const float* __restrict__ Lp,
                               float* __restrict__ out) {
    const int idx = blockIdx.x * 256 + threadIdx.x;
    const int r   = idx >> 6;
    const int c8  = (idx & 63) * 8;
    const float m0 = Mp[r], m1 = Mp[16384 + r];
    const float l0 = Lp[r], l1 = Lp[16384 + r];
    const float M  = fmaxf(m0, m1);
    const float e0 = exp2f(m0 - M), e1 = exp2f(m1 - M);
    const float invL = 1.f / (e0 * l0 + e1 * l1);
    const s16x8 a = __builtin_nontemporal_load(
        reinterpret_cast<const s16x8*>(Op + (size_t)r * 512 + c8));
    const s16x8 bq = __builtin_nontemporal_load(
        reinterpret_cast<const s16x8*>(Op + (size_t)16384 * 512 + (size_t)r * 512 + c8));
    float o[8];
    #pragma unroll
    for (int i = 0; i < 8; i++)
        o[i] = (bf2f((unsigned short)a[i]) * e0 + bf2f((unsigned short)bq[i]) * e1) * invL;
    f32x4* dst = reinterpret_cast<f32x4*>(out + (size_t)r * 512 + c8);
    __builtin_nontemporal_store((f32x4){o[0], o[1], o[2], o[3]}, dst);
    __builtin_nontemporal_store((f32x4){o[4], o[5], o[6], o[7]}, dst + 1);
}

// ---------------- launch ----------------

extern "C" void kernel_launch(void* const* d_in, const int* in_sizes, int n_in,
                              void* d_out, int out_size, void* d_ws, size_t ws_size,
                              hipStream_t stream) {
    const float* x     = (const float*)d_in[0];
    const float* adj   = (const float*)d_in[1];
    const float* Wq    = (const float*)d_in[2];
    const float* bq    = (const float*)d_in[3];
    const float* Wk    = (const float*)d_in[4];
    const float* bk    = (const float*)d_in[5];
    const float* Wv    = (const float*)d_in[6];
    const float* bv    = (const float*)d_in[7];
    const float* scale = (const float*)d_in[8];
    const float* width = (const float*)d_in[9];

    char* ws = (char*)d_ws;
    unsigned short* xb = (unsigned short*)(ws);
    unsigned short* WT = (unsigned short*)(ws + 16777216);
    unsigned short* Qb = (unsigned short*)(ws + 18350080);
    unsigned short* Kb = (unsigned short*)(ws + 35127296);
    unsigned short* VT = (unsigned short*)(ws + 51904512);
    unsigned short* Op = (unsigned short*)(ws + 68681728);
    float*          Mp = (float*)(ws + 102236160);
    float*          Lp = (float*)(ws + 102367232);
    float* out = (float*)d_out;

    hipLaunchKernelGGL(convert_x_kernel, dim3(8192), dim3(256), 0, stream, x, xb, 8388608 / 4);
    hipLaunchKernelGGL(transpose_w_kernel, dim3(8, 8, 3), dim3(256), 0, stream, Wq, Wk, Wv, WT);
    hipLaunchKernelGGL(proj_gemm_kernel, dim3(128, 4, 3), dim3(256), 0, stream,
                       xb, WT, bq, bk, bv, Qb, Kb, VT);
    hipLaunchKernelGGL(attn_kernel, dim3(16, 32), dim3(512), 0, stream,
                       Qb, Kb, VT, adj, scale, width, Op, Mp, Lp);
    hipLaunchKernelGGL(combine_kernel, dim3(4096), dim3(256), 0, stream, Op, Mp, Lp, out);
}